// Round 1
// baseline (76.314 us; speedup 1.0000x reference)
//
#include <hip/hip_runtime.h>
#include <hip/hip_bf16.h>
#include <math.h>

// Problem constants
#define BB 32
#define SS 2048
#define HH 1024
#define DD 1024
#define HD 2048
#define NSPLIT 16   // S-splits per batch for K2
#define KSPLIT 8    // K-splits for out GEMM
#define NEG_BIG -1e10f

__device__ __forceinline__ float wave_reduce_sum(float v) {
#pragma unroll
    for (int off = 32; off > 0; off >>= 1) v += __shfl_xor(v, off, 64);
    return v;
}

__device__ __forceinline__ float dot4(float4 a, float4 b) {
    return a.x * b.x + a.y * b.y + a.z * b.z + a.w * b.w;
}

// ---------------- K1: x = hidden @ W1^T  (B x D) ----------------
// grid 512 = B*16, block 256. Each wave computes 16 outputs.
__global__ __launch_bounds__(256) void k1_gemv_x(const float* __restrict__ hidden,
                                                 const float* __restrict__ W1,
                                                 float* __restrict__ x) {
    int b = blockIdx.x >> 4;
    int dt = blockIdx.x & 15;
    int tid = threadIdx.x;
    int w = tid >> 6, lane = tid & 63;
    const float4* hp = (const float4*)(hidden + (size_t)b * HH);
    float4 h0 = hp[lane], h1 = hp[lane + 64], h2 = hp[lane + 128], h3 = hp[lane + 192];
    int dbase = dt * 64 + w * 16;
#pragma unroll 4
    for (int i = 0; i < 16; ++i) {
        int d = dbase + i;
        const float4* wp = (const float4*)(W1 + (size_t)d * HH);
        float4 w0 = wp[lane], w1 = wp[lane + 64], w2 = wp[lane + 128], w3 = wp[lane + 192];
        float s = dot4(w0, h0) + dot4(w1, h1) + dot4(w2, h2) + dot4(w3, h3);
        s = wave_reduce_sum(s);
        if (lane == 0) x[b * DD + d] = s;
    }
}

// ---------------- K2: fused scores + online-softmax ctx partials ----------------
// grid 512 = B*NSPLIT, block 256 (4 waves). Each wave streams 32 rows of enc[b].
__global__ __launch_bounds__(256) void k2_fused(const float* __restrict__ enc,
                                                const float* __restrict__ x,
                                                const int* __restrict__ src_lens,
                                                float* __restrict__ scores,
                                                float* __restrict__ ctxp,
                                                float* __restrict__ m_part,
                                                float* __restrict__ l_part) {
    int b = blockIdx.x >> 4;
    int sp = blockIdx.x & 15;
    int tid = threadIdx.x;
    int w = tid >> 6, lane = tid & 63;

    const float4* xp = (const float4*)(x + (size_t)b * DD);
    float4 x0 = xp[lane], x1 = xp[lane + 64], x2 = xp[lane + 128], x3 = xp[lane + 192];
    int len = src_lens[b];
    int srow = sp * 128 + w * 32;

    float m = NEG_BIG, l = 0.f;
    float4 a0 = {0, 0, 0, 0}, a1 = {0, 0, 0, 0}, a2 = {0, 0, 0, 0}, a3 = {0, 0, 0, 0};

    for (int r = 0; r < 32; ++r) {
        int s = srow + r;
        const float4* ep = (const float4*)(enc + ((size_t)b * SS + s) * DD);
        float4 e0 = ep[lane], e1 = ep[lane + 64], e2 = ep[lane + 128], e3 = ep[lane + 192];
        float part = dot4(e0, x0) + dot4(e1, x1) + dot4(e2, x2) + dot4(e3, x3);
        part = wave_reduce_sum(part);  // butterfly: all lanes hold the sum
        float v = (s < len) ? part : 0.0f;
        if (v == 0.0f) v = NEG_BIG;  // torch quirk: exact zeros -> -1e10
        if (lane == 0) scores[b * SS + s] = v;
        if (v > m) {
            float sc = __expf(m - v);
            m = v;
            l *= sc;
            a0.x *= sc; a0.y *= sc; a0.z *= sc; a0.w *= sc;
            a1.x *= sc; a1.y *= sc; a1.z *= sc; a1.w *= sc;
            a2.x *= sc; a2.y *= sc; a2.z *= sc; a2.w *= sc;
            a3.x *= sc; a3.y *= sc; a3.z *= sc; a3.w *= sc;
        }
        float p = __expf(v - m);
        l += p;
        a0.x += p * e0.x; a0.y += p * e0.y; a0.z += p * e0.z; a0.w += p * e0.w;
        a1.x += p * e1.x; a1.y += p * e1.y; a1.z += p * e1.z; a1.w += p * e1.w;
        a2.x += p * e2.x; a2.y += p * e2.y; a2.z += p * e2.z; a2.w += p * e2.w;
        a3.x += p * e3.x; a3.y += p * e3.y; a3.z += p * e3.z; a3.w += p * e3.w;
    }

    // combine 4 waves within block
    __shared__ float4 lctx[4][256];
    __shared__ float lm[4], ll[4];
    lctx[w][lane] = a0;
    lctx[w][lane + 64] = a1;
    lctx[w][lane + 128] = a2;
    lctx[w][lane + 192] = a3;
    if (lane == 0) { lm[w] = m; ll[w] = l; }
    __syncthreads();

    float M = fmaxf(fmaxf(lm[0], lm[1]), fmaxf(lm[2], lm[3]));
    float s0 = __expf(lm[0] - M), s1 = __expf(lm[1] - M);
    float s2 = __expf(lm[2] - M), s3 = __expf(lm[3] - M);
    float L = s0 * ll[0] + s1 * ll[1] + s2 * ll[2] + s3 * ll[3];
    float4 c0 = lctx[0][tid], c1 = lctx[1][tid], c2 = lctx[2][tid], c3 = lctx[3][tid];
    float4 sum;
    sum.x = s0 * c0.x + s1 * c1.x + s2 * c2.x + s3 * c3.x;
    sum.y = s0 * c0.y + s1 * c1.y + s2 * c2.y + s3 * c3.y;
    sum.z = s0 * c0.z + s1 * c1.z + s2 * c2.z + s3 * c3.z;
    sum.w = s0 * c0.w + s1 * c1.w + s2 * c2.w + s3 * c3.w;
    // lctx[w][i] holds cols 256*(i/64) + 4*(i%64) .. +3
    int cc = ((tid >> 6) << 8) | ((tid & 63) << 2);
    *(float4*)(ctxp + ((size_t)(b * NSPLIT + sp)) * DD + cc) = sum;
    if (tid == 0) {
        m_part[b * NSPLIT + sp] = M;
        l_part[b * NSPLIT + sp] = L;
    }
}

// ---------------- K3: combine NSPLIT partials -> ctx, Mb, Lb ----------------
// grid B, block 256 (thread t owns cols 4t..4t+3)
__global__ __launch_bounds__(256) void k3_combine(const float* __restrict__ ctxp,
                                                  const float* __restrict__ m_part,
                                                  const float* __restrict__ l_part,
                                                  float* __restrict__ ctx,
                                                  float* __restrict__ Mb,
                                                  float* __restrict__ Lb) {
    int b = blockIdx.x;
    int tid = threadIdx.x;
    float M = -INFINITY;
#pragma unroll
    for (int k = 0; k < NSPLIT; ++k) M = fmaxf(M, m_part[b * NSPLIT + k]);
    float L = 0.f;
    float4 sum = {0, 0, 0, 0};
#pragma unroll
    for (int k = 0; k < NSPLIT; ++k) {
        float sc = __expf(m_part[b * NSPLIT + k] - M);
        L += sc * l_part[b * NSPLIT + k];
        float4 c = *(const float4*)(ctxp + ((size_t)(b * NSPLIT + k)) * DD + tid * 4);
        sum.x += sc * c.x; sum.y += sc * c.y; sum.z += sc * c.z; sum.w += sc * c.w;
    }
    float rL = 1.0f / L;
    float4 o = {sum.x * rL, sum.y * rL, sum.z * rL, sum.w * rL};
    *(float4*)(ctx + (size_t)b * DD + tid * 4) = o;
    if (tid == 0) { Mb[b] = M; Lb[b] = L; }
}

// ---------------- K5: out_part = cat([ctx,hidden]) @ W2^T (split-K) ----------------
// grid 256 = 32 dtiles * 8 ksplits, block 256. LDS tiles XOR-swizzled vs bank conflicts.
__global__ __launch_bounds__(256) void k5_outgemm(const float* __restrict__ ctx,
                                                  const float* __restrict__ hidden,
                                                  const float* __restrict__ W2,
                                                  float* __restrict__ outp) {
    int dt = blockIdx.x & 31;
    int ks = blockIdx.x >> 5;
    int tid = threadIdx.x;
    __shared__ float cat_s[32 * 128];
    __shared__ float w2_s[32 * 128];
    int b0 = tid & 15, b1 = b0 + 16;
    int dl0 = (tid >> 4) * 2, dl1 = dl0 + 1;
    float acc00 = 0.f, acc01 = 0.f, acc10 = 0.f, acc11 = 0.f;

    for (int c = 0; c < 2; ++c) {
        int j0 = ks * 256 + c * 128;
        __syncthreads();
#pragma unroll
        for (int pass = 0; pass < 4; ++pass) {
            int r = pass * 8 + (tid >> 5);
            int jj4 = tid & 31;
            int j = j0 + jj4 * 4;
            const float* src = (j < 1024) ? (ctx + (size_t)r * 1024 + j)
                                          : (hidden + (size_t)r * 1024 + (j - 1024));
            float4 v = *(const float4*)src;
            *(float4*)(cat_s + r * 128 + ((jj4 ^ (r & 7)) << 2)) = v;
            int dg = dt * 32 + r;
            float4 wv = *(const float4*)(W2 + (size_t)dg * HD + j);
            *(float4*)(w2_s + r * 128 + ((jj4 ^ (r & 7)) << 2)) = wv;
        }
        __syncthreads();
#pragma unroll 4
        for (int jj4 = 0; jj4 < 32; ++jj4) {
            float4 cA = *(const float4*)(cat_s + b0 * 128 + ((jj4 ^ (b0 & 7)) << 2));
            float4 cB = *(const float4*)(cat_s + b1 * 128 + ((jj4 ^ (b1 & 7)) << 2));
            float4 wA = *(const float4*)(w2_s + dl0 * 128 + ((jj4 ^ (dl0 & 7)) << 2));
            float4 wB = *(const float4*)(w2_s + dl1 * 128 + ((jj4 ^ (dl1 & 7)) << 2));
            acc00 += dot4(cA, wA);
            acc01 += dot4(cA, wB);
            acc10 += dot4(cB, wA);
            acc11 += dot4(cB, wB);
        }
    }
    float* op = outp + (size_t)ks * (BB * DD);
    op[b0 * 1024 + dt * 32 + dl0] = acc00;
    op[b0 * 1024 + dt * 32 + dl1] = acc01;
    op[b1 * 1024 + dt * 32 + dl0] = acc10;
    op[b1 * 1024 + dt * 32 + dl1] = acc11;
}

// ---------------- K6: finalize: out = tanh(sum partials); attn.T ----------------
// grid 384, block 256: 98304 threads = 32768 (out) + 65536 (attn.T)
__global__ __launch_bounds__(256) void k6_final(const float* __restrict__ outp,
                                                const float* __restrict__ scores,
                                                const float* __restrict__ Mb,
                                                const float* __restrict__ Lb,
                                                float* __restrict__ out) {
    int i = blockIdx.x * 256 + threadIdx.x;
    if (i < BB * DD) {
        float s = 0.f;
#pragma unroll
        for (int k = 0; k < KSPLIT; ++k) s += outp[(size_t)k * (BB * DD) + i];
        out[i] = tanhf(s);
    } else {
        int j = i - BB * DD;           // attn.T index: j = s*B + b
        int b = j & 31, sIdx = j >> 5;
        float v = __expf(scores[b * SS + sIdx] - Mb[b]) / Lb[b];
        out[i] = v;
    }
}

extern "C" void kernel_launch(void* const* d_in, const int* in_sizes, int n_in,
                              void* d_out, int out_size, void* d_ws, size_t ws_size,
                              hipStream_t stream) {
    const float* hidden = (const float*)d_in[0];
    const float* enc = (const float*)d_in[1];
    const int* src_lens = (const int*)d_in[2];
    const float* W1 = (const float*)d_in[3];
    const float* W2 = (const float*)d_in[4];
    float* out = (float*)d_out;
    float* ws = (float*)d_ws;

    // ws layout (floats)
    float* x = ws;                    // 32768
    float* scores = ws + 32768;       // 65536
    float* ctxp = ws + 98304;         // 32*16*1024 = 524288
    float* m_part = ws + 622592;      // 512
    float* l_part = ws + 623104;      // 512
    float* Mb = ws + 623616;          // 32
    float* Lb = ws + 623648;          // 32
    float* ctx = ws + 623680;         // 32768
    float* outp = ws + 656448;        // 8*32768 = 262144  (total ~3.7 MB)

    k1_gemv_x<<<512, 256, 0, stream>>>(hidden, W1, x);
    k2_fused<<<512, 256, 0, stream>>>(enc, x, src_lens, scores, ctxp, m_part, l_part);
    k3_combine<<<32, 256, 0, stream>>>(ctxp, m_part, l_part, ctx, Mb, Lb);
    k5_outgemm<<<256, 256, 0, stream>>>(ctx, hidden, W2, outp);
    k6_final<<<384, 256, 0, stream>>>(outp, scores, Mb, Lb, out);
}

// Round 2
// 76.272 us; speedup vs baseline: 1.0005x; 1.0005x over previous
//
#include <hip/hip_runtime.h>
#include <hip/hip_bf16.h>
#include <math.h>

// Problem constants
#define BB 32
#define SS 2048
#define HH 1024
#define DD 1024
#define HD 2048
#define NSPLIT 16   // S-splits per batch for K2
#define KSPLIT 8    // K-splits for out GEMM
#define NEG_BIG -1e10f

__device__ __forceinline__ float wave_reduce_sum(float v) {
#pragma unroll
    for (int off = 32; off > 0; off >>= 1) v += __shfl_xor(v, off, 64);
    return v;
}

__device__ __forceinline__ float dot4(float4 a, float4 b) {
    return a.x * b.x + a.y * b.y + a.z * b.z + a.w * b.w;
}

// ---------------- K1: x = hidden @ W1^T  (B x D) ----------------
// grid 256, block 256 (4 waves). One wave per output row d; W1 read ONCE.
// hidden (128 KB) staged in LDS in two 64 KB halves.
__global__ __launch_bounds__(256) void k1_gemv_x(const float* __restrict__ hidden,
                                                 const float* __restrict__ W1,
                                                 float* __restrict__ x) {
    __shared__ float4 hs[16 * 256];  // 64 KB: 16 batches of hidden
    int tid = threadIdx.x;
    int w = tid >> 6, lane = tid & 63;
    int d = blockIdx.x * 4 + w;
    const float4* wp = (const float4*)(W1 + (size_t)d * HH);
    float4 w0 = wp[lane], w1 = wp[lane + 64], w2 = wp[lane + 128], w3 = wp[lane + 192];
    const float4* hp = (const float4*)hidden;

    for (int half = 0; half < 2; ++half) {
        __syncthreads();
#pragma unroll
        for (int i = 0; i < 16; ++i) hs[i * 256 + tid] = hp[half * 4096 + i * 256 + tid];
        __syncthreads();
#pragma unroll 4
        for (int bl = 0; bl < 16; ++bl) {
            const float4* hb = hs + bl * 256;
            float s = dot4(hb[lane], w0) + dot4(hb[lane + 64], w1) +
                      dot4(hb[lane + 128], w2) + dot4(hb[lane + 192], w3);
            s = wave_reduce_sum(s);
            if (lane == 0) x[(half * 16 + bl) * DD + d] = s;
        }
    }
}

// ---------------- K2: fused scores + online-softmax ctx partials ----------------
// grid 512 = B*NSPLIT, block 512 (8 waves). Each wave streams 16 rows of enc[b].
__global__ __launch_bounds__(512) void k2_fused(const float* __restrict__ enc,
                                                const float* __restrict__ x,
                                                const int* __restrict__ src_lens,
                                                float* __restrict__ scores,
                                                float* __restrict__ ctxp,
                                                float* __restrict__ m_part,
                                                float* __restrict__ l_part) {
    int b = blockIdx.x >> 4;
    int sp = blockIdx.x & 15;
    int tid = threadIdx.x;
    int w = tid >> 6, lane = tid & 63;

    const float4* xp = (const float4*)(x + (size_t)b * DD);
    float4 x0 = xp[lane], x1 = xp[lane + 64], x2 = xp[lane + 128], x3 = xp[lane + 192];
    int len = src_lens[b];
    int srow = sp * 128 + w * 16;

    float m = NEG_BIG, l = 0.f;
    float4 a0 = {0, 0, 0, 0}, a1 = {0, 0, 0, 0}, a2 = {0, 0, 0, 0}, a3 = {0, 0, 0, 0};

    for (int r = 0; r < 16; ++r) {
        int s = srow + r;
        const float4* ep = (const float4*)(enc + ((size_t)b * SS + s) * DD);
        float4 e0 = ep[lane], e1 = ep[lane + 64], e2 = ep[lane + 128], e3 = ep[lane + 192];
        float part = dot4(e0, x0) + dot4(e1, x1) + dot4(e2, x2) + dot4(e3, x3);
        part = wave_reduce_sum(part);  // butterfly: all lanes hold the sum
        float v = (s < len) ? part : 0.0f;
        if (v == 0.0f) v = NEG_BIG;  // torch quirk: exact zeros -> -1e10
        if (lane == 0) scores[b * SS + s] = v;
        if (v > m) {  // wave-uniform branch
            float sc = __expf(m - v);
            m = v;
            l *= sc;
            a0.x *= sc; a0.y *= sc; a0.z *= sc; a0.w *= sc;
            a1.x *= sc; a1.y *= sc; a1.z *= sc; a1.w *= sc;
            a2.x *= sc; a2.y *= sc; a2.z *= sc; a2.w *= sc;
            a3.x *= sc; a3.y *= sc; a3.z *= sc; a3.w *= sc;
        }
        float p = __expf(v - m);
        l += p;
        a0.x += p * e0.x; a0.y += p * e0.y; a0.z += p * e0.z; a0.w += p * e0.w;
        a1.x += p * e1.x; a1.y += p * e1.y; a1.z += p * e1.z; a1.w += p * e1.w;
        a2.x += p * e2.x; a2.y += p * e2.y; a2.z += p * e2.z; a2.w += p * e2.w;
        a3.x += p * e3.x; a3.y += p * e3.y; a3.z += p * e3.z; a3.w += p * e3.w;
    }

    // combine 8 waves within block
    __shared__ float4 lctx[8][256];  // 32 KB
    __shared__ float lm[8], ll[8];
    lctx[w][lane] = a0;
    lctx[w][lane + 64] = a1;
    lctx[w][lane + 128] = a2;
    lctx[w][lane + 192] = a3;
    if (lane == 0) { lm[w] = m; ll[w] = l; }
    __syncthreads();

    if (tid < 256) {
        float M = lm[0];
#pragma unroll
        for (int k = 1; k < 8; ++k) M = fmaxf(M, lm[k]);
        float L = 0.f;
        float4 sum = {0, 0, 0, 0};
#pragma unroll
        for (int k = 0; k < 8; ++k) {
            float sc = __expf(lm[k] - M);
            L += sc * ll[k];
            float4 c = lctx[k][tid];
            sum.x += sc * c.x; sum.y += sc * c.y; sum.z += sc * c.z; sum.w += sc * c.w;
        }
        // lctx[k][i] holds cols 256*(i/64) + 4*(i%64) .. +3
        int cc = ((tid >> 6) << 8) | ((tid & 63) << 2);
        *(float4*)(ctxp + ((size_t)(b * NSPLIT + sp)) * DD + cc) = sum;
        if (tid == 0) {
            m_part[b * NSPLIT + sp] = M;
            l_part[b * NSPLIT + sp] = L;
        }
    }
}

// ---------------- K3: combine NSPLIT partials -> ctx, Mb, Lb ----------------
// grid B, block 256 (thread t owns cols 4t..4t+3)
__global__ __launch_bounds__(256) void k3_combine(const float* __restrict__ ctxp,
                                                  const float* __restrict__ m_part,
                                                  const float* __restrict__ l_part,
                                                  float* __restrict__ ctx,
                                                  float* __restrict__ Mb,
                                                  float* __restrict__ Lb) {
    int b = blockIdx.x;
    int tid = threadIdx.x;
    float M = -INFINITY;
#pragma unroll
    for (int k = 0; k < NSPLIT; ++k) M = fmaxf(M, m_part[b * NSPLIT + k]);
    float L = 0.f;
    float4 sum = {0, 0, 0, 0};
#pragma unroll
    for (int k = 0; k < NSPLIT; ++k) {
        float sc = __expf(m_part[b * NSPLIT + k] - M);
        L += sc * l_part[b * NSPLIT + k];
        float4 c = *(const float4*)(ctxp + ((size_t)(b * NSPLIT + k)) * DD + tid * 4);
        sum.x += sc * c.x; sum.y += sc * c.y; sum.z += sc * c.z; sum.w += sc * c.w;
    }
    float rL = 1.0f / L;
    float4 o = {sum.x * rL, sum.y * rL, sum.z * rL, sum.w * rL};
    *(float4*)(ctx + (size_t)b * DD + tid * 4) = o;
    if (tid == 0) { Mb[b] = M; Lb[b] = L; }
}

// ---------------- K5: out_part = cat([ctx,hidden]) @ W2^T (split-K) ----------------
// grid 256 = 32 dtiles * 8 ksplits, block 256. LDS tiles XOR-swizzled vs bank conflicts.
__global__ __launch_bounds__(256) void k5_outgemm(const float* __restrict__ ctx,
                                                  const float* __restrict__ hidden,
                                                  const float* __restrict__ W2,
                                                  float* __restrict__ outp) {
    int dt = blockIdx.x & 31;
    int ks = blockIdx.x >> 5;
    int tid = threadIdx.x;
    __shared__ float cat_s[32 * 128];
    __shared__ float w2_s[32 * 128];
    int b0 = tid & 15, b1 = b0 + 16;
    int dl0 = (tid >> 4) * 2, dl1 = dl0 + 1;
    float acc00 = 0.f, acc01 = 0.f, acc10 = 0.f, acc11 = 0.f;

    for (int c = 0; c < 2; ++c) {
        int j0 = ks * 256 + c * 128;
        __syncthreads();
#pragma unroll
        for (int pass = 0; pass < 4; ++pass) {
            int r = pass * 8 + (tid >> 5);
            int jj4 = tid & 31;
            int j = j0 + jj4 * 4;
            const float* src = (j < 1024) ? (ctx + (size_t)r * 1024 + j)
                                          : (hidden + (size_t)r * 1024 + (j - 1024));
            float4 v = *(const float4*)src;
            *(float4*)(cat_s + r * 128 + ((jj4 ^ (r & 7)) << 2)) = v;
            int dg = dt * 32 + r;
            float4 wv = *(const float4*)(W2 + (size_t)dg * HD + j);
            *(float4*)(w2_s + r * 128 + ((jj4 ^ (r & 7)) << 2)) = wv;
        }
        __syncthreads();
#pragma unroll 4
        for (int jj4 = 0; jj4 < 32; ++jj4) {
            float4 cA = *(const float4*)(cat_s + b0 * 128 + ((jj4 ^ (b0 & 7)) << 2));
            float4 cB = *(const float4*)(cat_s + b1 * 128 + ((jj4 ^ (b1 & 7)) << 2));
            float4 wA = *(const float4*)(w2_s + dl0 * 128 + ((jj4 ^ (dl0 & 7)) << 2));
            float4 wB = *(const float4*)(w2_s + dl1 * 128 + ((jj4 ^ (dl1 & 7)) << 2));
            acc00 += dot4(cA, wA);
            acc01 += dot4(cA, wB);
            acc10 += dot4(cB, wA);
            acc11 += dot4(cB, wB);
        }
    }
    float* op = outp + (size_t)ks * (BB * DD);
    op[b0 * 1024 + dt * 32 + dl0] = acc00;
    op[b0 * 1024 + dt * 32 + dl1] = acc01;
    op[b1 * 1024 + dt * 32 + dl0] = acc10;
    op[b1 * 1024 + dt * 32 + dl1] = acc11;
}

// ---------------- K6: finalize: out = tanh(sum partials); attn.T ----------------
// grid 384, block 256: 98304 threads = 32768 (out) + 65536 (attn.T)
__global__ __launch_bounds__(256) void k6_final(const float* __restrict__ outp,
                                                const float* __restrict__ scores,
                                                const float* __restrict__ Mb,
                                                const float* __restrict__ Lb,
                                                float* __restrict__ out) {
    int i = blockIdx.x * 256 + threadIdx.x;
    if (i < BB * DD) {
        float s = 0.f;
#pragma unroll
        for (int k = 0; k < KSPLIT; ++k) s += outp[(size_t)k * (BB * DD) + i];
        out[i] = tanhf(s);
    } else {
        int j = i - BB * DD;           // attn.T index: j = s*B + b
        int b = j & 31, sIdx = j >> 5;
        float v = __expf(scores[b * SS + sIdx] - Mb[b]) / Lb[b];
        out[i] = v;
    }
}

extern "C" void kernel_launch(void* const* d_in, const int* in_sizes, int n_in,
                              void* d_out, int out_size, void* d_ws, size_t ws_size,
                              hipStream_t stream) {
    const float* hidden = (const float*)d_in[0];
    const float* enc = (const float*)d_in[1];
    const int* src_lens = (const int*)d_in[2];
    const float* W1 = (const float*)d_in[3];
    const float* W2 = (const float*)d_in[4];
    float* out = (float*)d_out;
    float* ws = (float*)d_ws;

    // ws layout (floats)
    float* x = ws;                    // 32768
    float* scores = ws + 32768;       // 65536
    float* ctxp = ws + 98304;         // 32*16*1024 = 524288
    float* m_part = ws + 622592;      // 512
    float* l_part = ws + 623104;      // 512
    float* Mb = ws + 623616;          // 32
    float* Lb = ws + 623648;          // 32
    float* ctx = ws + 623680;         // 32768
    float* outp = ws + 656448;        // 8*32768 = 262144  (total ~3.7 MB)

    k1_gemv_x<<<256, 256, 0, stream>>>(hidden, W1, x);
    k2_fused<<<512, 512, 0, stream>>>(enc, x, src_lens, scores, ctxp, m_part, l_part);
    k3_combine<<<32, 256, 0, stream>>>(ctxp, m_part, l_part, ctx, Mb, Lb);
    k5_outgemm<<<256, 256, 0, stream>>>(ctx, hidden, W2, outp);
    k6_final<<<384, 256, 0, stream>>>(outp, scores, Mb, Lb, out);
}

// Round 3
// 59.947 us; speedup vs baseline: 1.2730x; 1.2723x over previous
//
#include <hip/hip_runtime.h>
#include <hip/hip_bf16.h>
#include <math.h>

// Problem constants
#define BB 32
#define SS 2048
#define HH 1024
#define DD 1024
#define HD 2048
#define NSPLIT 32   // S-splits per batch for K2 (64 rows per block)
#define KSPLIT 8    // K-splits for out GEMM
#define NEG_BIG -1e10f

__device__ __forceinline__ float wave_reduce_sum(float v) {
#pragma unroll
    for (int off = 32; off > 0; off >>= 1) v += __shfl_xor(v, off, 64);
    return v;
}

__device__ __forceinline__ float dot4(float4 a, float4 b) {
    return a.x * b.x + a.y * b.y + a.z * b.z + a.w * b.w;
}

// ---------------- K1: x = hidden @ W1^T  (B x D) ----------------
// grid 256, block 256 (4 waves). One wave per output row d; W1 read ONCE.
__global__ __launch_bounds__(256) void k1_gemv_x(const float* __restrict__ hidden,
                                                 const float* __restrict__ W1,
                                                 float* __restrict__ x) {
    __shared__ float4 hs[16 * 256];  // 64 KB: 16 batches of hidden
    int tid = threadIdx.x;
    int w = tid >> 6, lane = tid & 63;
    int d = blockIdx.x * 4 + w;
    const float4* wp = (const float4*)(W1 + (size_t)d * HH);
    float4 w0 = wp[lane], w1 = wp[lane + 64], w2 = wp[lane + 128], w3 = wp[lane + 192];
    const float4* hp = (const float4*)hidden;

    for (int half = 0; half < 2; ++half) {
        __syncthreads();
#pragma unroll
        for (int i = 0; i < 16; ++i) hs[i * 256 + tid] = hp[half * 4096 + i * 256 + tid];
        __syncthreads();
#pragma unroll 4
        for (int bl = 0; bl < 16; ++bl) {
            const float4* hb = hs + bl * 256;
            float s = dot4(hb[lane], w0) + dot4(hb[lane + 64], w1) +
                      dot4(hb[lane + 128], w2) + dot4(hb[lane + 192], w3);
            s = wave_reduce_sum(s);
            if (lane == 0) x[(half * 16 + bl) * DD + d] = s;
        }
    }
}

// ---------------- K2: fused scores + online-softmax ctx partials ----------------
// grid 1024 = B*NSPLIT, block 512 (8 waves x 8 rows). Rows with s >= len are
// NOT loaded: their softmax weight is exactly 0 in f32 (exp(-1e10 - M)).
__global__ __launch_bounds__(512) void k2_fused(const float* __restrict__ enc,
                                                const float* __restrict__ x,
                                                const int* __restrict__ src_lens,
                                                float* __restrict__ scores,
                                                float* __restrict__ ctxp,
                                                float* __restrict__ m_part,
                                                float* __restrict__ l_part) {
    int b = blockIdx.x >> 5;
    int sp = blockIdx.x & 31;
    int tid = threadIdx.x;
    int w = tid >> 6, lane = tid & 63;
    int len = src_lens[b];
    int srow = sp * 64 + w * 8;

    float m = NEG_BIG, l = 0.f;
    float4 a0 = {0, 0, 0, 0}, a1 = {0, 0, 0, 0}, a2 = {0, 0, 0, 0}, a3 = {0, 0, 0, 0};

    if (srow < len) {  // wave has at least one real row
        const float4* xp = (const float4*)(x + (size_t)b * DD);
        float4 x0 = xp[lane], x1 = xp[lane + 64], x2 = xp[lane + 128], x3 = xp[lane + 192];
        int rend = min(8, len - srow);
        for (int r = 0; r < rend; ++r) {
            int s = srow + r;
            const float4* ep = (const float4*)(enc + ((size_t)b * SS + s) * DD);
            float4 e0 = ep[lane], e1 = ep[lane + 64], e2 = ep[lane + 128], e3 = ep[lane + 192];
            float part = dot4(e0, x0) + dot4(e1, x1) + dot4(e2, x2) + dot4(e3, x3);
            part = wave_reduce_sum(part);  // butterfly: all lanes hold the sum
            float v = part;
            if (v == 0.0f) v = NEG_BIG;  // torch quirk: exact zeros -> -1e10
            if (lane == 0) scores[b * SS + s] = v;
            if (v > m) {  // wave-uniform
                float sc = __expf(m - v);  // == 0.0 on first real row (m = -1e10)
                m = v;
                l *= sc;
                a0.x *= sc; a0.y *= sc; a0.z *= sc; a0.w *= sc;
                a1.x *= sc; a1.y *= sc; a1.z *= sc; a1.w *= sc;
                a2.x *= sc; a2.y *= sc; a2.z *= sc; a2.w *= sc;
                a3.x *= sc; a3.y *= sc; a3.z *= sc; a3.w *= sc;
            }
            float p = __expf(v - m);
            l += p;
            a0.x += p * e0.x; a0.y += p * e0.y; a0.z += p * e0.z; a0.w += p * e0.w;
            a1.x += p * e1.x; a1.y += p * e1.y; a1.z += p * e1.z; a1.w += p * e1.w;
            a2.x += p * e2.x; a2.y += p * e2.y; a2.z += p * e2.z; a2.w += p * e2.w;
            a3.x += p * e3.x; a3.y += p * e3.y; a3.z += p * e3.z; a3.w += p * e3.w;
        }
    }
    // masked rows: score = -1e10, zero softmax weight, no enc load
    {
        int s0 = max(srow, len);
        for (int s = s0 + lane; s < srow + 8; s += 64) scores[b * SS + s] = NEG_BIG;
    }

    // combine 8 waves within block
    __shared__ float4 lctx[8][256];  // 32 KB
    __shared__ float lm[8], ll[8];
    lctx[w][lane] = a0;
    lctx[w][lane + 64] = a1;
    lctx[w][lane + 128] = a2;
    lctx[w][lane + 192] = a3;
    if (lane == 0) { lm[w] = m; ll[w] = l; }
    __syncthreads();

    if (tid < 256) {
        float M = lm[0];
#pragma unroll
        for (int k = 1; k < 8; ++k) M = fmaxf(M, lm[k]);
        float L = 0.f;
        float4 sum = {0, 0, 0, 0};
#pragma unroll
        for (int k = 0; k < 8; ++k) {
            float sc = __expf(lm[k] - M);  // empty waves: exp(-1e10 - M) == 0
            L += sc * ll[k];
            float4 c = lctx[k][tid];
            sum.x += sc * c.x; sum.y += sc * c.y; sum.z += sc * c.z; sum.w += sc * c.w;
        }
        // lctx[k][i] holds cols 256*(i/64) + 4*(i%64) .. +3
        int cc = ((tid >> 6) << 8) | ((tid & 63) << 2);
        *(float4*)(ctxp + ((size_t)(b * NSPLIT + sp)) * DD + cc) = sum;
        if (tid == 0) {
            m_part[b * NSPLIT + sp] = M;
            l_part[b * NSPLIT + sp] = L;
        }
    }
}

// ---------------- K3: combine NSPLIT partials -> ctx, Mb, Lb ----------------
// grid B, block 256 (thread t owns cols 4t..4t+3)
__global__ __launch_bounds__(256) void k3_combine(const float* __restrict__ ctxp,
                                                  const float* __restrict__ m_part,
                                                  const float* __restrict__ l_part,
                                                  float* __restrict__ ctx,
                                                  float* __restrict__ Mb,
                                                  float* __restrict__ Lb) {
    int b = blockIdx.x;
    int tid = threadIdx.x;
    float M = -INFINITY;
#pragma unroll
    for (int k = 0; k < NSPLIT; ++k) M = fmaxf(M, m_part[b * NSPLIT + k]);
    float L = 0.f;
    float4 sum = {0, 0, 0, 0};
#pragma unroll
    for (int k = 0; k < NSPLIT; ++k) {
        float sc = __expf(m_part[b * NSPLIT + k] - M);
        L += sc * l_part[b * NSPLIT + k];
        float4 c = *(const float4*)(ctxp + ((size_t)(b * NSPLIT + k)) * DD + tid * 4);
        sum.x += sc * c.x; sum.y += sc * c.y; sum.z += sc * c.z; sum.w += sc * c.w;
    }
    float rL = 1.0f / L;
    float4 o = {sum.x * rL, sum.y * rL, sum.z * rL, sum.w * rL};
    *(float4*)(ctx + (size_t)b * DD + tid * 4) = o;
    if (tid == 0) { Mb[b] = M; Lb[b] = L; }
}

// ---------------- K5: out_part = cat([ctx,hidden]) @ W2^T (split-K) ----------------
// grid 256 = 32 dtiles * 8 ksplits, block 256. LDS tiles XOR-swizzled vs bank conflicts.
__global__ __launch_bounds__(256) void k5_outgemm(const float* __restrict__ ctx,
                                                  const float* __restrict__ hidden,
                                                  const float* __restrict__ W2,
                                                  float* __restrict__ outp) {
    int dt = blockIdx.x & 31;
    int ks = blockIdx.x >> 5;
    int tid = threadIdx.x;
    __shared__ float cat_s[32 * 128];
    __shared__ float w2_s[32 * 128];
    int b0 = tid & 15, b1 = b0 + 16;
    int dl0 = (tid >> 4) * 2, dl1 = dl0 + 1;
    float acc00 = 0.f, acc01 = 0.f, acc10 = 0.f, acc11 = 0.f;

    for (int c = 0; c < 2; ++c) {
        int j0 = ks * 256 + c * 128;
        __syncthreads();
#pragma unroll
        for (int pass = 0; pass < 4; ++pass) {
            int r = pass * 8 + (tid >> 5);
            int jj4 = tid & 31;
            int j = j0 + jj4 * 4;
            const float* src = (j < 1024) ? (ctx + (size_t)r * 1024 + j)
                                          : (hidden + (size_t)r * 1024 + (j - 1024));
            float4 v = *(const float4*)src;
            *(float4*)(cat_s + r * 128 + ((jj4 ^ (r & 7)) << 2)) = v;
            int dg = dt * 32 + r;
            float4 wv = *(const float4*)(W2 + (size_t)dg * HD + j);
            *(float4*)(w2_s + r * 128 + ((jj4 ^ (r & 7)) << 2)) = wv;
        }
        __syncthreads();
#pragma unroll 4
        for (int jj4 = 0; jj4 < 32; ++jj4) {
            float4 cA = *(const float4*)(cat_s + b0 * 128 + ((jj4 ^ (b0 & 7)) << 2));
            float4 cB = *(const float4*)(cat_s + b1 * 128 + ((jj4 ^ (b1 & 7)) << 2));
            float4 wA = *(const float4*)(w2_s + dl0 * 128 + ((jj4 ^ (dl0 & 7)) << 2));
            float4 wB = *(const float4*)(w2_s + dl1 * 128 + ((jj4 ^ (dl1 & 7)) << 2));
            acc00 += dot4(cA, wA);
            acc01 += dot4(cA, wB);
            acc10 += dot4(cB, wA);
            acc11 += dot4(cB, wB);
        }
    }
    float* op = outp + (size_t)ks * (BB * DD);
    op[b0 * 1024 + dt * 32 + dl0] = acc00;
    op[b0 * 1024 + dt * 32 + dl1] = acc01;
    op[b1 * 1024 + dt * 32 + dl0] = acc10;
    op[b1 * 1024 + dt * 32 + dl1] = acc11;
}

// ---------------- K6: finalize: out = tanh(sum partials); attn.T ----------------
// grid 384, block 256: 98304 threads = 32768 (out) + 65536 (attn.T)
__global__ __launch_bounds__(256) void k6_final(const float* __restrict__ outp,
                                                const float* __restrict__ scores,
                                                const float* __restrict__ Mb,
                                                const float* __restrict__ Lb,
                                                float* __restrict__ out) {
    int i = blockIdx.x * 256 + threadIdx.x;
    if (i < BB * DD) {
        float s = 0.f;
#pragma unroll
        for (int k = 0; k < KSPLIT; ++k) s += outp[(size_t)k * (BB * DD) + i];
        out[i] = tanhf(s);
    } else {
        int j = i - BB * DD;           // attn.T index: j = s*B + b
        int b = j & 31, sIdx = j >> 5;
        float v = __expf(scores[b * SS + sIdx] - Mb[b]) / Lb[b];
        out[i] = v;
    }
}

extern "C" void kernel_launch(void* const* d_in, const int* in_sizes, int n_in,
                              void* d_out, int out_size, void* d_ws, size_t ws_size,
                              hipStream_t stream) {
    const float* hidden = (const float*)d_in[0];
    const float* enc = (const float*)d_in[1];
    const int* src_lens = (const int*)d_in[2];
    const float* W1 = (const float*)d_in[3];
    const float* W2 = (const float*)d_in[4];
    float* out = (float*)d_out;
    float* ws = (float*)d_ws;

    // ws layout (floats)
    float* x = ws;                       // 32768
    float* scores = ws + 32768;          // 65536
    float* ctxp = ws + 98304;            // 32*32*1024 = 1048576
    float* m_part = ws + 1146880;        // 1024
    float* l_part = ws + 1147904;        // 1024
    float* Mb = ws + 1148928;            // 32
    float* Lb = ws + 1148960;            // 32
    float* ctx = ws + 1148992;           // 32768
    float* outp = ws + 1181760;          // 8*32768 = 262144  (total ~5.8 MB)

    k1_gemv_x<<<256, 256, 0, stream>>>(hidden, W1, x);
    k2_fused<<<1024, 512, 0, stream>>>(enc, x, src_lens, scores, ctxp, m_part, l_part);
    k3_combine<<<32, 256, 0, stream>>>(ctxp, m_part, l_part, ctx, Mb, Lb);
    k5_outgemm<<<256, 256, 0, stream>>>(ctx, hidden, W2, outp);
    k6_final<<<384, 256, 0, stream>>>(outp, scores, Mb, Lb, out);
}

// Round 4
// 59.941 us; speedup vs baseline: 1.2732x; 1.0001x over previous
//
#include <hip/hip_runtime.h>
#include <hip/hip_bf16.h>
#include <math.h>

// Problem constants
#define BB 32
#define SS 2048
#define HH 1024
#define DD 1024
#define HD 2048
#define NSPLIT 32   // 64-row chunks per batch (max)
#define KSPLIT 16   // K-splits for out GEMM
#define NEG_BIG -1e10f

__device__ __forceinline__ float wave_reduce_sum(float v) {
#pragma unroll
    for (int off = 32; off > 0; off >>= 1) v += __shfl_xor(v, off, 64);
    return v;
}

__device__ __forceinline__ float dot4(float4 a, float4 b) {
    return a.x * b.x + a.y * b.y + a.z * b.z + a.w * b.w;
}

// ---------------- K1: x = hidden @ W1^T  (B x D) ----------------
// grid 256, block 256 (4 waves). One wave per output row d; W1 read ONCE.
__global__ __launch_bounds__(256) void k1_gemv_x(const float* __restrict__ hidden,
                                                 const float* __restrict__ W1,
                                                 float* __restrict__ x) {
    __shared__ float4 hs[16 * 256];  // 64 KB: 16 batches of hidden
    int tid = threadIdx.x;
    int w = tid >> 6, lane = tid & 63;
    int d = blockIdx.x * 4 + w;
    const float4* wp = (const float4*)(W1 + (size_t)d * HH);
    float4 w0 = wp[lane], w1 = wp[lane + 64], w2 = wp[lane + 128], w3 = wp[lane + 192];
    const float4* hp = (const float4*)hidden;

    for (int half = 0; half < 2; ++half) {
        __syncthreads();
#pragma unroll
        for (int i = 0; i < 16; ++i) hs[i * 256 + tid] = hp[half * 4096 + i * 256 + tid];
        __syncthreads();
#pragma unroll 4
        for (int bl = 0; bl < 16; ++bl) {
            const float4* hb = hs + bl * 256;
            float s = dot4(hb[lane], w0) + dot4(hb[lane + 64], w1) +
                      dot4(hb[lane + 128], w2) + dot4(hb[lane + 192], w3);
            s = wave_reduce_sum(s);
            if (lane == 0) x[(half * 16 + bl) * DD + d] = s;
        }
    }
}

// ---------------- K2: fused scores + online-softmax ctx partials ----------------
// grid 512, block 512 (8 waves x 8 rows per 64-row chunk). Busy chunks are
// flattened via an in-block prefix over ceil(len/64) and grid-strided ->
// per-CU load balance regardless of src_lens distribution.
__global__ __launch_bounds__(512) void k2_fused(const float* __restrict__ enc,
                                                const float* __restrict__ x,
                                                const int* __restrict__ src_lens,
                                                float* __restrict__ scores,
                                                float* __restrict__ ctxp,
                                                float* __restrict__ m_part,
                                                float* __restrict__ l_part) {
    int tid = threadIdx.x;
    int w = tid >> 6, lane = tid & 63;

    __shared__ int pfx[BB + 1];
    if (tid == 0) {
        int a = 0;
        pfx[0] = 0;
#pragma unroll
        for (int b = 0; b < BB; ++b) {
            a += (src_lens[b] + 63) >> 6;
            pfx[b + 1] = a;
        }
    }
    __shared__ float4 lctx[8][256];  // 32 KB
    __shared__ float lm[8], ll[8];
    __syncthreads();
    int total = pfx[BB];

    for (int chunk = blockIdx.x; chunk < total; chunk += gridDim.x) {
        int b = 0;
        while (pfx[b + 1] <= chunk) ++b;  // uniform, <=32 iters
        int sp = chunk - pfx[b];
        int len = src_lens[b];
        int srow = sp * 64 + w * 8;

        float m = NEG_BIG, l = 0.f;
        float4 a0 = {0, 0, 0, 0}, a1 = {0, 0, 0, 0}, a2 = {0, 0, 0, 0}, a3 = {0, 0, 0, 0};

        if (srow < len) {  // wave has at least one real row
            const float4* xp = (const float4*)(x + (size_t)b * DD);
            float4 x0 = xp[lane], x1 = xp[lane + 64], x2 = xp[lane + 128], x3 = xp[lane + 192];
            int rend = min(8, len - srow);
            for (int r = 0; r < rend; ++r) {
                int s = srow + r;
                const float4* ep = (const float4*)(enc + ((size_t)b * SS + s) * DD);
                float4 e0 = ep[lane], e1 = ep[lane + 64], e2 = ep[lane + 128], e3 = ep[lane + 192];
                float part = dot4(e0, x0) + dot4(e1, x1) + dot4(e2, x2) + dot4(e3, x3);
                part = wave_reduce_sum(part);  // butterfly: all lanes hold the sum
                float v = part;
                if (v == 0.0f) v = NEG_BIG;  // torch quirk: exact zeros -> -1e10
                if (lane == 0) scores[b * SS + s] = v;
                if (v > m) {  // wave-uniform
                    float sc = __expf(m - v);  // == 0.0 on first real row
                    m = v;
                    l *= sc;
                    a0.x *= sc; a0.y *= sc; a0.z *= sc; a0.w *= sc;
                    a1.x *= sc; a1.y *= sc; a1.z *= sc; a1.w *= sc;
                    a2.x *= sc; a2.y *= sc; a2.z *= sc; a2.w *= sc;
                    a3.x *= sc; a3.y *= sc; a3.z *= sc; a3.w *= sc;
                }
                float p = __expf(v - m);
                l += p;
                a0.x += p * e0.x; a0.y += p * e0.y; a0.z += p * e0.z; a0.w += p * e0.w;
                a1.x += p * e1.x; a1.y += p * e1.y; a1.z += p * e1.z; a1.w += p * e1.w;
                a2.x += p * e2.x; a2.y += p * e2.y; a2.z += p * e2.z; a2.w += p * e2.w;
                a3.x += p * e3.x; a3.y += p * e3.y; a3.z += p * e3.z; a3.w += p * e3.w;
            }
        }
        // rows >= len: untouched. K6 emits attn=0 for them (exp(-1e10-M)==0).

        lctx[w][lane] = a0;
        lctx[w][lane + 64] = a1;
        lctx[w][lane + 128] = a2;
        lctx[w][lane + 192] = a3;
        if (lane == 0) { lm[w] = m; ll[w] = l; }
        __syncthreads();

        if (tid < 256) {
            float M = lm[0];
#pragma unroll
            for (int k = 1; k < 8; ++k) M = fmaxf(M, lm[k]);
            float L = 0.f;
            float4 sum = {0, 0, 0, 0};
#pragma unroll
            for (int k = 0; k < 8; ++k) {
                float sc = __expf(lm[k] - M);  // empty waves contribute 0
                L += sc * ll[k];
                float4 c = lctx[k][tid];
                sum.x += sc * c.x; sum.y += sc * c.y; sum.z += sc * c.z; sum.w += sc * c.w;
            }
            // lctx[k][i] holds cols 256*(i/64) + 4*(i%64) .. +3
            int cc = ((tid >> 6) << 8) | ((tid & 63) << 2);
            *(float4*)(ctxp + ((size_t)(b * NSPLIT + sp)) * DD + cc) = sum;
            if (tid == 0) {
                m_part[b * NSPLIT + sp] = M;
                l_part[b * NSPLIT + sp] = L;
            }
        }
        __syncthreads();  // protect lctx reuse on next chunk
    }
}

// ---------------- K3: combine busy partials -> ctx, Mb, Lb ----------------
// grid 128 = B*4 (one block per (b, 256-col tile)), block 256.
__global__ __launch_bounds__(256) void k3_combine(const float* __restrict__ ctxp,
                                                  const float* __restrict__ m_part,
                                                  const float* __restrict__ l_part,
                                                  const int* __restrict__ src_lens,
                                                  float* __restrict__ ctx,
                                                  float* __restrict__ Mb,
                                                  float* __restrict__ Lb) {
    int b = blockIdx.x >> 2;
    int col = (blockIdx.x & 3) * 256 + threadIdx.x;
    int nb = (src_lens[b] + 63) >> 6;  // busy chunks for this batch
    float M = NEG_BIG;
    for (int k = 0; k < nb; ++k) M = fmaxf(M, m_part[b * NSPLIT + k]);
    float L = 0.f;
    float sum = 0.f;
    for (int k = 0; k < nb; ++k) {
        float sc = __expf(m_part[b * NSPLIT + k] - M);
        L += sc * l_part[b * NSPLIT + k];
        sum += sc * ctxp[((size_t)(b * NSPLIT + k)) * DD + col];
    }
    ctx[(size_t)b * DD + col] = sum / L;
    if (threadIdx.x == 0 && (blockIdx.x & 3) == 0) { Mb[b] = M; Lb[b] = L; }
}

// ---------------- K5: out_part = cat([ctx,hidden]) @ W2^T (split-K) ----------------
// grid 512 = 32 dtiles * 16 ksplits, block 256. LDS tiles XOR-swizzled.
__global__ __launch_bounds__(256) void k5_outgemm(const float* __restrict__ ctx,
                                                  const float* __restrict__ hidden,
                                                  const float* __restrict__ W2,
                                                  float* __restrict__ outp) {
    int dt = blockIdx.x & 31;
    int ks = blockIdx.x >> 5;
    int tid = threadIdx.x;
    __shared__ float cat_s[32 * 128];
    __shared__ float w2_s[32 * 128];
    int b0 = tid & 15, b1 = b0 + 16;
    int dl0 = (tid >> 4) * 2, dl1 = dl0 + 1;
    float acc00 = 0.f, acc01 = 0.f, acc10 = 0.f, acc11 = 0.f;

    int j0 = ks * 128;
#pragma unroll
    for (int pass = 0; pass < 4; ++pass) {
        int r = pass * 8 + (tid >> 5);
        int jj4 = tid & 31;
        int j = j0 + jj4 * 4;
        const float* src = (j < 1024) ? (ctx + (size_t)r * 1024 + j)
                                      : (hidden + (size_t)r * 1024 + (j - 1024));
        float4 v = *(const float4*)src;
        *(float4*)(cat_s + r * 128 + ((jj4 ^ (r & 7)) << 2)) = v;
        int dg = dt * 32 + r;
        float4 wv = *(const float4*)(W2 + (size_t)dg * HD + j);
        *(float4*)(w2_s + r * 128 + ((jj4 ^ (r & 7)) << 2)) = wv;
    }
    __syncthreads();
#pragma unroll 4
    for (int jj4 = 0; jj4 < 32; ++jj4) {
        float4 cA = *(const float4*)(cat_s + b0 * 128 + ((jj4 ^ (b0 & 7)) << 2));
        float4 cB = *(const float4*)(cat_s + b1 * 128 + ((jj4 ^ (b1 & 7)) << 2));
        float4 wA = *(const float4*)(w2_s + dl0 * 128 + ((jj4 ^ (dl0 & 7)) << 2));
        float4 wB = *(const float4*)(w2_s + dl1 * 128 + ((jj4 ^ (dl1 & 7)) << 2));
        acc00 += dot4(cA, wA);
        acc01 += dot4(cA, wB);
        acc10 += dot4(cB, wA);
        acc11 += dot4(cB, wB);
    }
    float* op = outp + (size_t)ks * (BB * DD);
    op[b0 * 1024 + dt * 32 + dl0] = acc00;
    op[b0 * 1024 + dt * 32 + dl1] = acc01;
    op[b1 * 1024 + dt * 32 + dl0] = acc10;
    op[b1 * 1024 + dt * 32 + dl1] = acc11;
}

// ---------------- K6: finalize: out = tanh(sum partials); attn.T ----------------
// grid 384, block 256: 98304 threads = 32768 (out) + 65536 (attn.T)
__global__ __launch_bounds__(256) void k6_final(const float* __restrict__ outp,
                                                const float* __restrict__ scores,
                                                const int* __restrict__ src_lens,
                                                const float* __restrict__ Mb,
                                                const float* __restrict__ Lb,
                                                float* __restrict__ out) {
    int i = blockIdx.x * 256 + threadIdx.x;
    if (i < BB * DD) {
        float s = 0.f;
#pragma unroll
        for (int k = 0; k < KSPLIT; ++k) s += outp[(size_t)k * (BB * DD) + i];
        out[i] = tanhf(s);
    } else {
        int j = i - BB * DD;           // attn.T index: j = s*B + b
        int b = j & 31, sIdx = j >> 5;
        float v = 0.0f;                // rows >= len: exp(-1e10 - M) == 0 exactly
        if (sIdx < src_lens[b]) v = __expf(scores[b * SS + sIdx] - Mb[b]) / Lb[b];
        out[i] = v;
    }
}

extern "C" void kernel_launch(void* const* d_in, const int* in_sizes, int n_in,
                              void* d_out, int out_size, void* d_ws, size_t ws_size,
                              hipStream_t stream) {
    const float* hidden = (const float*)d_in[0];
    const float* enc = (const float*)d_in[1];
    const int* src_lens = (const int*)d_in[2];
    const float* W1 = (const float*)d_in[3];
    const float* W2 = (const float*)d_in[4];
    float* out = (float*)d_out;
    float* ws = (float*)d_ws;

    // ws layout (floats)
    float* x = ws;                       // 32768
    float* scores = ws + 32768;          // 65536
    float* ctxp = ws + 98304;            // 32*32*1024 = 1048576
    float* m_part = ws + 1146880;        // 1024
    float* l_part = ws + 1147904;        // 1024
    float* Mb = ws + 1148928;            // 32
    float* Lb = ws + 1148960;            // 32
    float* ctx = ws + 1148992;           // 32768
    float* outp = ws + 1181760;          // 16*32768 = 524288  (total ~6.8 MB)

    k1_gemv_x<<<256, 256, 0, stream>>>(hidden, W1, x);
    k2_fused<<<512, 512, 0, stream>>>(enc, x, src_lens, scores, ctxp, m_part, l_part);
    k3_combine<<<128, 256, 0, stream>>>(ctxp, m_part, l_part, src_lens, ctx, Mb, Lb);
    k5_outgemm<<<512, 256, 0, stream>>>(ctx, hidden, W2, outp);
    k6_final<<<384, 256, 0, stream>>>(outp, scores, src_lens, Mb, Lb, out);
}